// Round 13
// baseline (159.973 us; speedup 1.0000x reference)
//
#include <hip/hip_runtime.h>
#include <math.h>

// PointWarping: B=4, C=3, N=8192 fp32. Exact 3-NN via spatial grid + IDW warp.
//
// 6 dispatches:
//  k_zero  : zero 2*NCT counts (DB cells + query cells)
//  k_count : fused binning of DB points (pos1+flow1) AND queries (pos2)
//  k_scan1 : block-local scan over 2*NCT counts (+ re-zero for ranks)
//  k_final : per-block base from 211 partials + apply + offs[2NCT]
//  k_scat  : fused scatter: DB -> packed csr float4, queries -> qlist int
//  k_cohort: ONE WAVE PER QUERY CELL. Stage the cell's 5x5x5 candidate set
//            (<=768) into LDS once (64-lane coalesced, R6 column+binsearch
//            mapping), then process the cell's queries 4-at-a-time in 16-lane
//            groups from LDS. Failed/OOR/overflow queries: inline wave-coop
//            brute scan. Amortizes candidate loads over ~5.4 queries/cell.
//
// Exactness: cells h=0.22 on [-3.3,3.3]^3 (clamped). Any DB point excluded
// from the 5x5x5 block is >= 2h=0.44 away (clamped DB points are at least as
// far as their cell box), so d3 <= 0.44^2*0.999 proves the top-3 exact.
// Queries outside the grid range always fall back. Keys are exact u64
// (d2_bits<<32|idx): fp32-exact, (d2,idx)-lex == top_k tie-break, independent
// of atomic rank order.

#define BB 4
#define NN 8192
#define BBNN (BB * NN)            // 32768
#define NC 30
#define NCELLS (NC * NC * NC)     // 27000
#define NCT (BB * NCELLS)        // 108000
#define NCT2 (2 * NCT)            // 216000
#define GRID_R 3.3f
#define GRID_INVH (1.0f / 0.22f)
#define D3_THR (0.44f * 0.44f * 0.999f)
#define EPB 1024
#define SB 211                    // ceil(NCT2/EPB)
#define CANDCAP 768               // LDS candidates per wave (block lambda ~620)

typedef unsigned long long u64;

__device__ __forceinline__ int cell_of(float x) {
  int c = (int)floorf((x + GRID_R) * GRID_INVH);
  return min(max(c, 0), NC - 1);
}

__device__ __forceinline__ void merge3(u64& a0, u64& a1, u64& a2,
                                       u64 b0, u64 b1, u64 b2) {
  const u64 lo0 = a0 < b0 ? a0 : b0;
  const u64 hi0 = a0 < b0 ? b0 : a0;
  const u64 lo1 = a1 < b1 ? a1 : b1;
  const u64 lo2 = a2 < b2 ? a2 : b2;
  const u64 o1 = hi0 < lo1 ? hi0 : lo1;
  const u64 t = hi0 < lo1 ? lo1 : hi0;
  a0 = lo0;
  a1 = o1;
  a2 = t < lo2 ? t : lo2;
}

__device__ __forceinline__ void insert3(u64& s0, u64& s1, u64& s2, u64 key) {
  const bool c0 = key < s0;
  const bool c1 = key < s1;
  const bool c2 = key < s2;
  s2 = c1 ? s1 : (c2 ? key : s2);
  s1 = c0 ? s0 : (c1 ? key : s1);
  s0 = c0 ? key : s0;
}

__device__ __forceinline__ void wave_merge3(u64& s0, u64& s1, u64& s2) {
#pragma unroll
  for (int mask = 32; mask >= 1; mask >>= 1) {
    const u64 b0 = __shfl_xor(s0, mask, 64);
    const u64 b1 = __shfl_xor(s1, mask, 64);
    const u64 b2 = __shfl_xor(s2, mask, 64);
    merge3(s0, s1, s2, b0, b1, b2);
  }
}

__device__ __forceinline__ void cand1(const float4& a, float qx, float qy,
                                      float qz, u64& s0, u64& s1, u64& s2) {
  const float dx = a.x - qx, dy = a.y - qy, dz = a.z - qz;
  const float d2 = fmaf(dx, dx, fmaf(dy, dy, dz * dz));
  insert3(s0, s1, s2,
          ((u64)__float_as_uint(d2) << 32) | (unsigned)__float_as_uint(a.w));
}

__device__ __forceinline__ void idw_out(int b, int qn, float qx, float qy,
                                        float qz, u64 s0, u64 s1, u64 s2,
                                        const float* __restrict__ P1,
                                        const float* __restrict__ F1,
                                        float* __restrict__ out) {
  const int idxs[3] = {(int)(unsigned)s0 & (NN - 1),
                       (int)(unsigned)s1 & (NN - 1),
                       (int)(unsigned)s2 & (NN - 1)};
  float w[3], gfx[3], gfy[3], gfz[3];
  float wsumv = 0.0f;
#pragma unroll
  for (int r = 0; r < 3; ++r) {
    const int idx = idxs[r];
    const float fx = F1[idx], fy = F1[NN + idx], fz = F1[2 * NN + idx];
    const float kx = P1[idx] + fx;
    const float ky = P1[NN + idx] + fy;
    const float kz = P1[2 * NN + idx] + fz;
    const float dx = kx - qx, dy = ky - qy, dz = kz - qz;
    float d = sqrtf(dx * dx + dy * dy + dz * dz);
    d = fmaxf(d, 1e-10f);
    const float inv = 1.0f / d;
    w[r] = inv; wsumv += inv;
    gfx[r] = fx; gfy[r] = fy; gfz[r] = fz;
  }
  const float invw = 1.0f / wsumv;
  float ox = 0.0f, oy = 0.0f, oz = 0.0f;
#pragma unroll
  for (int r = 0; r < 3; ++r) {
    const float ww = w[r] * invw;
    ox = fmaf(ww, gfx[r], ox);
    oy = fmaf(ww, gfy[r], oy);
    oz = fmaf(ww, gfz[r], oz);
  }
  ox = qx - ox; oy = qy - oy; oz = qz - oz;
  ox = fminf(fmaxf(ox, -10.0f), 10.0f);
  oy = fminf(fmaxf(oy, -10.0f), 10.0f);
  oz = fminf(fmaxf(oz, -10.0f), 10.0f);
  float* o = out + (size_t)b * 3 * NN;
  o[qn] = ox;
  o[NN + qn] = oy;
  o[2 * NN + qn] = oz;
}

__global__ __launch_bounds__(256) void k_zero(int4* __restrict__ p) {
  const int i = blockIdx.x * 256 + threadIdx.x;
  if (i < NCT2 / 4) p[i] = make_int4(0, 0, 0, 0);
}

__global__ __launch_bounds__(256) void k_count(const float* __restrict__ p1,
                                               const float* __restrict__ p2,
                                               const float* __restrict__ f1,
                                               int* __restrict__ counts) {
  const int gid = blockIdx.x * 256 + threadIdx.x;  // 0..65535
  const bool isq = gid >= BBNN;
  const int id = isq ? gid - BBNN : gid;
  const int b = id >> 13, n = id & (NN - 1);
  float x, y, z;
  if (isq) {
    const float* P = p2 + (size_t)b * 3 * NN;
    x = P[n]; y = P[NN + n]; z = P[2 * NN + n];
  } else {
    const float* P = p1 + (size_t)b * 3 * NN;
    const float* F = f1 + (size_t)b * 3 * NN;
    x = P[n] + F[n]; y = P[NN + n] + F[NN + n]; z = P[2 * NN + n] + F[2 * NN + n];
  }
  const int cid = (cell_of(z) * NC + cell_of(y)) * NC + cell_of(x);
  const int g = (isq ? NCT : 0) + b * NCELLS + cid;
  atomicAdd(&counts[g], 1);
}

__global__ __launch_bounds__(256) void k_scan1(int* __restrict__ counts,
                                               int* __restrict__ offs,
                                               int* __restrict__ partials) {
  __shared__ int wsums[4];
  const int tid = threadIdx.x, lane = tid & 63, wav = tid >> 6;
  const int c = blockIdx.x * EPB + tid * 4;
  int4 v = make_int4(0, 0, 0, 0);
  if (c < NCT2) {
    v = *reinterpret_cast<const int4*>(counts + c);
    *reinterpret_cast<int4*>(counts + c) = make_int4(0, 0, 0, 0);  // rank reset
  }
  const int sum4 = v.x + v.y + v.z + v.w;
  int incl = sum4;
  for (int off = 1; off < 64; off <<= 1) {
    const int t = __shfl_up(incl, off, 64);
    incl += (lane >= off) ? t : 0;
  }
  if (lane == 63) wsums[wav] = incl;
  __syncthreads();
  int wbase = 0;
#pragma unroll
  for (int w = 0; w < 4; ++w) wbase += (w < wav) ? wsums[w] : 0;
  const int excl = wbase + incl - sum4;
  if (c < NCT2) {
    int4 e;
    e.x = excl;
    e.y = excl + v.x;
    e.z = e.y + v.y;
    e.w = e.z + v.z;
    *reinterpret_cast<int4*>(offs + c) = e;
  }
  if (tid == 255) partials[blockIdx.x] = wbase + incl;
}

__global__ __launch_bounds__(256) void k_final(int* __restrict__ offs,
                                               const int* __restrict__ partials) {
  __shared__ int sbase;
  const int tid = threadIdx.x, lane = tid & 63;
  const int bid = blockIdx.x;
  if (tid < 64) {
    int v = 0;
#pragma unroll
    for (int k = 0; k < 4; ++k) {
      const int j = lane + 64 * k;
      if (j < bid) v += partials[j];
    }
    for (int off = 32; off >= 1; off >>= 1) v += __shfl_down(v, off, 64);
    if (lane == 0) sbase = v;
  }
  __syncthreads();
  const int base = sbase;
  const int c = bid * EPB + tid * 4;
  if (c < NCT2) {
    int4 v = *reinterpret_cast<const int4*>(offs + c);
    v.x += base; v.y += base; v.z += base; v.w += base;
    *reinterpret_cast<int4*>(offs + c) = v;
  }
  if (bid == 0 && tid == 0) offs[NCT2] = 2 * BBNN;
}

__global__ __launch_bounds__(256) void k_scat(const float* __restrict__ p1,
                                              const float* __restrict__ p2,
                                              const float* __restrict__ f1,
                                              int* __restrict__ counts,
                                              const int* __restrict__ offs,
                                              float4* __restrict__ csr,
                                              int* __restrict__ qlist) {
  const int gid = blockIdx.x * 256 + threadIdx.x;  // 0..65535
  const bool isq = gid >= BBNN;
  const int id = isq ? gid - BBNN : gid;
  const int b = id >> 13, n = id & (NN - 1);
  float x, y, z;
  if (isq) {
    const float* P = p2 + (size_t)b * 3 * NN;
    x = P[n]; y = P[NN + n]; z = P[2 * NN + n];
  } else {
    const float* P = p1 + (size_t)b * 3 * NN;
    const float* F = f1 + (size_t)b * 3 * NN;
    x = P[n] + F[n]; y = P[NN + n] + F[NN + n]; z = P[2 * NN + n] + F[2 * NN + n];
  }
  const int cid = (cell_of(z) * NC + cell_of(y)) * NC + cell_of(x);
  const int g = (isq ? NCT : 0) + b * NCELLS + cid;
  const int rank = atomicAdd(&counts[g], 1);
  const int pos = offs[g] + rank;
  if (isq) qlist[pos - BBNN] = n;
  else csr[pos] = make_float4(x, y, z, __int_as_float(n));
}

// one wave per query cell; stage 5x5x5 candidates to LDS; 4 queries per pass.
__global__ __launch_bounds__(256) void k_cohort(const float* __restrict__ p1,
                                                const float* __restrict__ p2,
                                                const float* __restrict__ f1,
                                                const int* __restrict__ offs,
                                                const float4* __restrict__ csr,
                                                const int* __restrict__ qlist,
                                                float* __restrict__ out) {
  __shared__ float4 cand[4][CANDCAP];
  __shared__ int cumA[4][32];
  __shared__ int adjA[4][32];
  const int tid = threadIdx.x, lane = tid & 63, wav = tid >> 6;
  const int cell = blockIdx.x * 4 + wav;  // 0..NCT-1
  const int b = cell / NCELLS;
  const int cc = cell - b * NCELLS;

  const int qoff = offs[NCT + cell];
  const int qcnt = offs[NCT + cell + 1] - qoff;
  if (qcnt == 0) return;

  const float* P1 = p1 + (size_t)b * 3 * NN;
  const float* P2 = p2 + (size_t)b * 3 * NN;
  const float* F1 = f1 + (size_t)b * 3 * NN;

  const int cz = cc / 900;
  const int rem = cc - cz * 900;
  const int cy = rem / 30;
  const int cx = rem - cy * 30;

  // 25 (dz,dy) columns; x-run of <=5 cells is CSR-contiguous
  const int gxl = max(cx - 2, 0);
  const int span = min(cx + 2, NC - 1) - gxl + 1;
  const int cb = b * NCELLS;
  int n_c = 0, st_c = 0;
  if (lane < 25) {
    const int dzi = (lane * 205) >> 10;  // lane/5
    const int gz = cz + dzi - 2;
    const int gy = cy + (lane - dzi * 5) - 2;
    if (((unsigned)gz < NC) & ((unsigned)gy < NC)) {
      const int ia = cb + (gz * NC + gy) * NC + gxl;
      st_c = offs[ia];
      n_c = offs[ia + span] - st_c;
    }
  }
  int incl = n_c;
  for (int off = 1; off < 64; off <<= 1) {
    const int v = __shfl_up(incl, off, 64);
    incl += (lane >= off) ? v : 0;
  }
  const int excl = incl - n_c;
  const int T = __shfl(incl, 24, 64);
  if (lane < 32) {
    cumA[wav][lane] = excl;          // lanes 25..31 hold T (sentinel)
    adjA[wav][lane] = st_c - excl;
  }
  const bool bigfb = T > CANDCAP;

  if (!bigfb) {
    for (int g0 = 0; g0 < T; g0 += 64) {
      const int g = g0 + lane;
      if (g < T) {
        int c = 0;
#pragma unroll
        for (int st = 16; st >= 1; st >>= 1) {
          const int c2 = c + st;
          c = (cumA[wav][c2] <= g) ? c2 : c;
        }
        cand[wav][g] = csr[adjA[wav][c] + g];
      }
    }
    asm volatile("s_waitcnt lgkmcnt(0)" ::: "memory");
    __builtin_amdgcn_sched_barrier(0);
  }

  const int group = lane >> 4;   // 0..3
  const int sl = lane & 15;

  for (int q0 = 0; q0 < qcnt; q0 += 4) {
    const int qsel = q0 + group;
    const bool vq = qsel < qcnt;
    const int qn = qlist[qoff - BBNN + (vq ? qsel : 0)];
    const float qx = P2[qn], qy = P2[NN + qn], qz = P2[2 * NN + qn];
    const bool oor = !(fabsf(qx) < GRID_R && fabsf(qy) < GRID_R && fabsf(qz) < GRID_R);

    u64 s0 = ~0ULL, s1 = ~0ULL, s2 = ~0ULL;
    if (!bigfb && !oor) {
      for (int j = sl; j < T; j += 16) {
        cand1(cand[wav][j], qx, qy, qz, s0, s1, s2);
      }
    }
    // merge within the 16-lane group
#pragma unroll
    for (int mask = 1; mask <= 8; mask <<= 1) {
      const u64 b0 = __shfl_xor(s0, mask, 64);
      const u64 b1 = __shfl_xor(s1, mask, 64);
      const u64 b2 = __shfl_xor(s2, mask, 64);
      merge3(s0, s1, s2, b0, b1, b2);
    }
    const float d3 = __uint_as_float((unsigned)(s2 >> 32));
    const bool ok = vq && !bigfb && !oor && (d3 <= D3_THR);  // NaN-safe

    if (sl == 0 && ok) idw_out(b, qn, qx, qy, qz, s0, s1, s2, P1, F1, out);

    // wave-cooperative brute for this pass's failed queries
    const u64 bal = __ballot(sl == 0 && vq && !ok);
    if (bal != 0) {
#pragma unroll
      for (int q = 0; q < 4; ++q) {
        if (!((bal >> (16 * q)) & 1ULL)) continue;
        const int fqn = __shfl(qn, 16 * q, 64);
        const float fqx = __shfl(qx, 16 * q, 64);
        const float fqy = __shfl(qy, 16 * q, 64);
        const float fqz = __shfl(qz, 16 * q, 64);
        u64 a0 = ~0ULL, a1 = ~0ULL, a2 = ~0ULL;
        for (int t = 0; t < NN / 64; ++t) {
          const int g = t * 64 + lane;
          const float x = P1[g] + F1[g];
          const float y = P1[NN + g] + F1[NN + g];
          const float z = P1[2 * NN + g] + F1[2 * NN + g];
          const float dx = x - fqx, dy = y - fqy, dz = z - fqz;
          const float d2 = fmaf(dx, dx, fmaf(dy, dy, dz * dz));
          insert3(a0, a1, a2, ((u64)__float_as_uint(d2) << 32) | (unsigned)g);
        }
        wave_merge3(a0, a1, a2);
        if (lane == 0) idw_out(b, fqn, fqx, fqy, fqz, a0, a1, a2, P1, F1, out);
      }
    }
  }
}

extern "C" void kernel_launch(void* const* d_in, const int* in_sizes, int n_in,
                              void* d_out, int out_size, void* d_ws, size_t ws_size,
                              hipStream_t stream) {
  const float* pos1 = (const float*)d_in[0];
  const float* pos2 = (const float*)d_in[1];
  const float* flow1 = (const float*)d_in[2];
  float* out = (float*)d_out;

  // ws layout (16B-aligned sections)
  char* ws = (char*)d_ws;
  int* counts = (int*)ws;                                   // NCT2 ints
  size_t offs_off = ((size_t)NCT2 * 4 + 15) & ~(size_t)15;
  int* offs = (int*)(ws + offs_off);                        // NCT2+1 ints
  size_t part_off = (offs_off + ((size_t)NCT2 + 1) * 4 + 15) & ~(size_t)15;
  int* partials = (int*)(ws + part_off);                    // SB ints
  size_t ql_off = (part_off + (size_t)SB * 4 + 15) & ~(size_t)15;
  int* qlist = (int*)(ws + ql_off);                         // BBNN ints
  size_t csr_off = (ql_off + (size_t)BBNN * 4 + 15) & ~(size_t)15;
  float4* csr = (float4*)(ws + csr_off);                    // BBNN float4

  k_zero<<<dim3((NCT2 / 4 + 255) / 256), dim3(256), 0, stream>>>((int4*)counts);
  k_count<<<dim3(2 * BBNN / 256), dim3(256), 0, stream>>>(pos1, pos2, flow1, counts);
  k_scan1<<<dim3(SB), dim3(256), 0, stream>>>(counts, offs, partials);
  k_final<<<dim3(SB), dim3(256), 0, stream>>>(offs, partials);
  k_scat<<<dim3(2 * BBNN / 256), dim3(256), 0, stream>>>(pos1, pos2, flow1, counts,
                                                         offs, csr, qlist);
  k_cohort<<<dim3(NCT / 4), dim3(256), 0, stream>>>(pos1, pos2, flow1, offs, csr,
                                                    qlist, out);
}

// Round 14
// 72.496 us; speedup vs baseline: 2.2067x; 2.2067x over previous
//
#include <hip/hip_runtime.h>
#include <math.h>

// PointWarping: B=4, C=3, N=8192 fp32. Exact 3-NN via spatial grid + IDW warp.
//
// R10 structure + cell-sorted query processing (R12's reuse via cache, not LDS):
//  k_zero  : zero 2*NCT counts + fbcnt[4]
//  k_count : fused binning of DB points (pos1+flow1) AND queries (pos2)
//  k_scan1 : block-local scan over 2*NCT counts (+ re-zero for ranks)
//  k_final : per-block base from 211 partials + apply
//  k_scat  : DB -> packed csr float4; queries -> qlist (cell-sorted id)
//  k_query : 16 lanes/query, queries taken in qlist (cell) order ->
//            adjacent groups/waves read the same offs + CSR lines (L1 hits).
//            4-wide candidate batching; butterfly merge; failed -> queue.
//  k_fallback : block per 2 queued queries, 4-wide streamed brute scan.
//
// Exactness: cells h=0.22 on [-3.3,3.3]^3 (clamped). Any DB point >=3 cells
// away in some axis is > 2h=0.44 away, so if the 3rd-best d^2 within the
// 5x5x5 block is <= 0.44^2*0.999 the top-3 is exact; else brute-scan (also
// out-of-range queries). Keys are exact u64 (d2_bits<<32|idx): fp32-exact,
// (d2,idx)-lex == top_k tie-break, independent of atomic rank order (query
// processing ORDER varies with the race, but each query's result does not).

#define BB 4
#define NN 8192
#define BBNN (BB * NN)            // 32768
#define NC 30
#define NCELLS (NC * NC * NC)     // 27000
#define NCT (BB * NCELLS)         // 108000
#define NCT2 (2 * NCT)            // 216000
#define GRID_R 3.3f
#define GRID_INVH (1.0f / 0.22f)
#define D3_THR (0.44f * 0.44f * 0.999f)
#define EPB 1024
#define SB 211                    // ceil(NCT2/EPB)
#define NZ4 (NCT2 / 4 + 1)        // counts (54000 int4) + fbcnt[4]

typedef unsigned long long u64;

__device__ __forceinline__ int cell_of(float x) {
  int c = (int)floorf((x + GRID_R) * GRID_INVH);
  return min(max(c, 0), NC - 1);
}

__device__ __forceinline__ void merge3(u64& a0, u64& a1, u64& a2,
                                       u64 b0, u64 b1, u64 b2) {
  const u64 lo0 = a0 < b0 ? a0 : b0;
  const u64 hi0 = a0 < b0 ? b0 : a0;
  const u64 lo1 = a1 < b1 ? a1 : b1;
  const u64 lo2 = a2 < b2 ? a2 : b2;
  const u64 o1 = hi0 < lo1 ? hi0 : lo1;
  const u64 t = hi0 < lo1 ? lo1 : hi0;
  a0 = lo0;
  a1 = o1;
  a2 = t < lo2 ? t : lo2;
}

__device__ __forceinline__ void insert3(u64& s0, u64& s1, u64& s2, u64 key) {
  const bool c0 = key < s0;
  const bool c1 = key < s1;
  const bool c2 = key < s2;
  s2 = c1 ? s1 : (c2 ? key : s2);
  s1 = c0 ? s0 : (c1 ? key : s1);
  s0 = c0 ? key : s0;
}

__device__ __forceinline__ void wave_merge3(u64& s0, u64& s1, u64& s2) {
#pragma unroll
  for (int mask = 32; mask >= 1; mask >>= 1) {
    const u64 b0 = __shfl_xor(s0, mask, 64);
    const u64 b1 = __shfl_xor(s1, mask, 64);
    const u64 b2 = __shfl_xor(s2, mask, 64);
    merge3(s0, s1, s2, b0, b1, b2);
  }
}

__device__ __forceinline__ void cand1(const float4& a, float qx, float qy,
                                      float qz, u64& s0, u64& s1, u64& s2) {
  const float dx = a.x - qx, dy = a.y - qy, dz = a.z - qz;
  const float d2 = fmaf(dx, dx, fmaf(dy, dy, dz * dz));
  insert3(s0, s1, s2,
          ((u64)__float_as_uint(d2) << 32) | (unsigned)__float_as_uint(a.w));
}

// IDW epilogue for one query (indices from low words of s0..s2)
__device__ __forceinline__ void idw_out(int b, int qn, float qx, float qy,
                                        float qz, u64 s0, u64 s1, u64 s2,
                                        const float* __restrict__ P1,
                                        const float* __restrict__ F1,
                                        float* __restrict__ out) {
  const int idxs[3] = {(int)(unsigned)s0 & (NN - 1),
                       (int)(unsigned)s1 & (NN - 1),
                       (int)(unsigned)s2 & (NN - 1)};
  float w[3], gfx[3], gfy[3], gfz[3];
  float wsumv = 0.0f;
#pragma unroll
  for (int r = 0; r < 3; ++r) {
    const int idx = idxs[r];
    const float fx = F1[idx], fy = F1[NN + idx], fz = F1[2 * NN + idx];
    const float kx = P1[idx] + fx;
    const float ky = P1[NN + idx] + fy;
    const float kz = P1[2 * NN + idx] + fz;
    const float dx = kx - qx, dy = ky - qy, dz = kz - qz;
    float d = sqrtf(dx * dx + dy * dy + dz * dz);
    d = fmaxf(d, 1e-10f);
    const float inv = 1.0f / d;
    w[r] = inv; wsumv += inv;
    gfx[r] = fx; gfy[r] = fy; gfz[r] = fz;
  }
  const float invw = 1.0f / wsumv;
  float ox = 0.0f, oy = 0.0f, oz = 0.0f;
#pragma unroll
  for (int r = 0; r < 3; ++r) {
    const float ww = w[r] * invw;
    ox = fmaf(ww, gfx[r], ox);
    oy = fmaf(ww, gfy[r], oy);
    oz = fmaf(ww, gfz[r], oz);
  }
  ox = qx - ox; oy = qy - oy; oz = qz - oz;
  ox = fminf(fmaxf(ox, -10.0f), 10.0f);
  oy = fminf(fmaxf(oy, -10.0f), 10.0f);
  oz = fminf(fmaxf(oz, -10.0f), 10.0f);
  float* o = out + (size_t)b * 3 * NN;
  o[qn] = ox;
  o[NN + qn] = oy;
  o[2 * NN + qn] = oz;
}

__global__ __launch_bounds__(256) void k_zero(int4* __restrict__ p) {
  const int i = blockIdx.x * 256 + threadIdx.x;
  if (i < NZ4) p[i] = make_int4(0, 0, 0, 0);
}

__global__ __launch_bounds__(256) void k_count(const float* __restrict__ p1,
                                               const float* __restrict__ p2,
                                               const float* __restrict__ f1,
                                               int* __restrict__ counts) {
  const int gid = blockIdx.x * 256 + threadIdx.x;  // 0..65535
  const bool isq = gid >= BBNN;
  const int id = isq ? gid - BBNN : gid;
  const int b = id >> 13, n = id & (NN - 1);
  float x, y, z;
  if (isq) {
    const float* P = p2 + (size_t)b * 3 * NN;
    x = P[n]; y = P[NN + n]; z = P[2 * NN + n];
  } else {
    const float* P = p1 + (size_t)b * 3 * NN;
    const float* F = f1 + (size_t)b * 3 * NN;
    x = P[n] + F[n]; y = P[NN + n] + F[NN + n]; z = P[2 * NN + n] + F[2 * NN + n];
  }
  const int cid = (cell_of(z) * NC + cell_of(y)) * NC + cell_of(x);
  const int g = (isq ? NCT : 0) + b * NCELLS + cid;
  atomicAdd(&counts[g], 1);
}

__global__ __launch_bounds__(256) void k_scan1(int* __restrict__ counts,
                                               int* __restrict__ offs,
                                               int* __restrict__ partials) {
  __shared__ int wsums[4];
  const int tid = threadIdx.x, lane = tid & 63, wav = tid >> 6;
  const int c = blockIdx.x * EPB + tid * 4;
  int4 v = make_int4(0, 0, 0, 0);
  if (c < NCT2) {
    v = *reinterpret_cast<const int4*>(counts + c);
    *reinterpret_cast<int4*>(counts + c) = make_int4(0, 0, 0, 0);  // rank reset
  }
  const int sum4 = v.x + v.y + v.z + v.w;
  int incl = sum4;
  for (int off = 1; off < 64; off <<= 1) {
    const int t = __shfl_up(incl, off, 64);
    incl += (lane >= off) ? t : 0;
  }
  if (lane == 63) wsums[wav] = incl;
  __syncthreads();
  int wbase = 0;
#pragma unroll
  for (int w = 0; w < 4; ++w) wbase += (w < wav) ? wsums[w] : 0;
  const int excl = wbase + incl - sum4;
  if (c < NCT2) {
    int4 e;
    e.x = excl;
    e.y = excl + v.x;
    e.z = e.y + v.y;
    e.w = e.z + v.z;
    *reinterpret_cast<int4*>(offs + c) = e;
  }
  if (tid == 255) partials[blockIdx.x] = wbase + incl;
}

__global__ __launch_bounds__(256) void k_final(int* __restrict__ offs,
                                               const int* __restrict__ partials) {
  __shared__ int sbase;
  const int tid = threadIdx.x, lane = tid & 63;
  const int bid = blockIdx.x;
  if (tid < 64) {
    int v = 0;
#pragma unroll
    for (int k = 0; k < 4; ++k) {
      const int j = lane + 64 * k;
      if (j < bid) v += partials[j];
    }
    for (int off = 32; off >= 1; off >>= 1) v += __shfl_down(v, off, 64);
    if (lane == 0) sbase = v;
  }
  __syncthreads();
  const int base = sbase;
  const int c = bid * EPB + tid * 4;
  if (c < NCT2) {
    int4 v = *reinterpret_cast<const int4*>(offs + c);
    v.x += base; v.y += base; v.z += base; v.w += base;
    *reinterpret_cast<int4*>(offs + c) = v;
  }
  if (bid == 0 && tid == 0) offs[NCT2] = 2 * BBNN;
}

__global__ __launch_bounds__(256) void k_scat(const float* __restrict__ p1,
                                              const float* __restrict__ p2,
                                              const float* __restrict__ f1,
                                              int* __restrict__ counts,
                                              const int* __restrict__ offs,
                                              float4* __restrict__ csr,
                                              int* __restrict__ qlist) {
  const int gid = blockIdx.x * 256 + threadIdx.x;  // 0..65535
  const bool isq = gid >= BBNN;
  const int id = isq ? gid - BBNN : gid;
  const int b = id >> 13, n = id & (NN - 1);
  float x, y, z;
  if (isq) {
    const float* P = p2 + (size_t)b * 3 * NN;
    x = P[n]; y = P[NN + n]; z = P[2 * NN + n];
  } else {
    const float* P = p1 + (size_t)b * 3 * NN;
    const float* F = f1 + (size_t)b * 3 * NN;
    x = P[n] + F[n]; y = P[NN + n] + F[NN + n]; z = P[2 * NN + n] + F[2 * NN + n];
  }
  const int cid = (cell_of(z) * NC + cell_of(y)) * NC + cell_of(x);
  const int g = (isq ? NCT : 0) + b * NCELLS + cid;
  const int rank = atomicAdd(&counts[g], 1);
  const int pos = offs[g] + rank;
  if (isq) qlist[pos - BBNN] = id;   // cell-sorted query id (b*NN+n)
  else csr[pos] = make_float4(x, y, z, __int_as_float(n));
}

// column range for column index c (0..24) of the query's cell
__device__ __forceinline__ void col_range(int c, int qcy, int qcz, int cb,
                                          int gxl, int span,
                                          const int* __restrict__ offs,
                                          int& st, int& en) {
  const int dzi = (c * 205) >> 10;  // c/5 for c<=24
  const int gz = qcz + dzi - 2;
  const int gy = qcy + (c - dzi * 5) - 2;
  st = 0; en = 0;
  if (((unsigned)gz < NC) & ((unsigned)gy < NC)) {
    const int ia = cb + (gz * NC + gy) * NC + gxl;
    st = offs[ia];
    en = offs[ia + span];
  }
}

// scan one contiguous CSR run with 4-wide load batching
__device__ __forceinline__ void scan_col(int st, int en,
                                         const float4* __restrict__ csr,
                                         float qx, float qy, float qz,
                                         u64& s0, u64& s1, u64& s2) {
  int j = st;
  for (; j + 4 <= en; j += 4) {
    const float4 a = csr[j];
    const float4 b = csr[j + 1];
    const float4 c = csr[j + 2];
    const float4 d = csr[j + 3];
    cand1(a, qx, qy, qz, s0, s1, s2);
    cand1(b, qx, qy, qz, s0, s1, s2);
    cand1(c, qx, qy, qz, s0, s1, s2);
    cand1(d, qx, qy, qz, s0, s1, s2);
  }
  for (; j < en; ++j) {
    const float4 a = csr[j];
    cand1(a, qx, qy, qz, s0, s1, s2);
  }
}

// 16 lanes per query, queries in qlist (cell-sorted) order.
__global__ __launch_bounds__(256) void k_query(const float* __restrict__ p1,
                                               const float* __restrict__ p2,
                                               const float* __restrict__ f1,
                                               const int* __restrict__ offs,
                                               const float4* __restrict__ csr,
                                               const int* __restrict__ qlist,
                                               float* __restrict__ out,
                                               int* __restrict__ fbcnt,
                                               int* __restrict__ fbq) {
  const int gtid = blockIdx.x * 256 + threadIdx.x;  // 0..524287
  const int e = gtid >> 4;         // cell-sorted query slot
  const int r = gtid & 15;
  const int qid = qlist[e];        // b*NN + n (broadcast within group)
  const int b = qid >> 13;
  const int qn = qid & (NN - 1);
  const float* P1 = p1 + (size_t)b * 3 * NN;
  const float* P2 = p2 + (size_t)b * 3 * NN;
  const float* F1 = f1 + (size_t)b * 3 * NN;

  const float qx = P2[qn], qy = P2[NN + qn], qz = P2[2 * NN + qn];
  const bool oor = !(fabsf(qx) < GRID_R && fabsf(qy) < GRID_R && fabsf(qz) < GRID_R);

  u64 s0 = ~0ULL, s1 = ~0ULL, s2 = ~0ULL;

  if (!oor) {
    const int qcx = cell_of(qx), qcy = cell_of(qy), qcz = cell_of(qz);
    const int gxl = max(qcx - 2, 0);
    const int span = min(qcx + 2, NC - 1) - gxl + 1;
    const int cb = b * NCELLS;

    int st0, en0, st1 = 0, en1 = 0;
    col_range(r, qcy, qcz, cb, gxl, span, offs, st0, en0);
    if (r < 9) col_range(r + 16, qcy, qcz, cb, gxl, span, offs, st1, en1);

    scan_col(st0, en0, csr, qx, qy, qz, s0, s1, s2);
    scan_col(st1, en1, csr, qx, qy, qz, s0, s1, s2);
  }

  // merge the 16 partial triples of this query (4 butterfly steps)
#pragma unroll
  for (int mask = 1; mask <= 8; mask <<= 1) {
    const u64 b0 = __shfl_xor(s0, mask, 64);
    const u64 b1 = __shfl_xor(s1, mask, 64);
    const u64 b2 = __shfl_xor(s2, mask, 64);
    merge3(s0, s1, s2, b0, b1, b2);
  }

  if (r == 0) {
    const float d3 = __uint_as_float((unsigned)(s2 >> 32));
    const bool ok = !oor && (d3 <= D3_THR);  // NaN-safe: <3 cands -> fallback
    if (!ok) {
      const int slot = atomicAdd(&fbcnt[b], 1);
      fbq[b * NN + slot] = qn;
    } else {
      idw_out(b, qn, qx, qy, qz, s0, s1, s2, P1, F1, out);
    }
  }
}

// block per 2 queued queries; 256 threads stream all 8192 points, 4-wide.
__global__ __launch_bounds__(256) void k_fallback(const float* __restrict__ p1,
                                                  const float* __restrict__ p2,
                                                  const float* __restrict__ f1,
                                                  const int* __restrict__ fbcnt,
                                                  const int* __restrict__ fbq,
                                                  float* __restrict__ out) {
  __shared__ u64 redA[4][3];
  __shared__ u64 redC[4][3];
  const int b = blockIdx.y;
  const int nfb = fbcnt[b];
  const int tid = threadIdx.x, lane = tid & 63, wav = tid >> 6;
  const float* P1 = p1 + (size_t)b * 3 * NN;
  const float* P2 = p2 + (size_t)b * 3 * NN;
  const float* F1 = f1 + (size_t)b * 3 * NN;
  const int* q = fbq + b * NN;

  for (int base = blockIdx.x * 2; base < nfb; base += gridDim.x * 2) {
    const bool v1 = base + 1 < nfb;
    const int qn0 = q[base] & (NN - 1);
    const int qn1 = (v1 ? q[base + 1] : q[base]) & (NN - 1);
    const float q0x = P2[qn0], q0y = P2[NN + qn0], q0z = P2[2 * NN + qn0];
    const float q1x = P2[qn1], q1y = P2[NN + qn1], q1z = P2[2 * NN + qn1];

    u64 a0 = ~0ULL, a1 = ~0ULL, a2 = ~0ULL;
    u64 c0 = ~0ULL, c1 = ~0ULL, c2 = ~0ULL;

    for (int g0 = 0; g0 < NN; g0 += 1024) {
      const int g = g0 + tid;
      float xs[4], ys[4], zs[4];
#pragma unroll
      for (int k = 0; k < 4; ++k) {
        const int gg = g + k * 256;
        xs[k] = P1[gg] + F1[gg];
        ys[k] = P1[NN + gg] + F1[NN + gg];
        zs[k] = P1[2 * NN + gg] + F1[2 * NN + gg];
      }
#pragma unroll
      for (int k = 0; k < 4; ++k) {
        const unsigned gg = (unsigned)(g + k * 256);
        {
          const float dx = xs[k] - q0x, dy = ys[k] - q0y, dz = zs[k] - q0z;
          const float d2 = fmaf(dx, dx, fmaf(dy, dy, dz * dz));
          insert3(a0, a1, a2, ((u64)__float_as_uint(d2) << 32) | gg);
        }
        {
          const float dx = xs[k] - q1x, dy = ys[k] - q1y, dz = zs[k] - q1z;
          const float d2 = fmaf(dx, dx, fmaf(dy, dy, dz * dz));
          insert3(c0, c1, c2, ((u64)__float_as_uint(d2) << 32) | gg);
        }
      }
    }

    wave_merge3(a0, a1, a2);
    wave_merge3(c0, c1, c2);
    if (lane == 0) {
      redA[wav][0] = a0; redA[wav][1] = a1; redA[wav][2] = a2;
      redC[wav][0] = c0; redC[wav][1] = c1; redC[wav][2] = c2;
    }
    __syncthreads();
    if (tid == 0) {
      u64 m0 = redA[0][0], m1 = redA[0][1], m2 = redA[0][2];
#pragma unroll
      for (int w = 1; w < 4; ++w) merge3(m0, m1, m2, redA[w][0], redA[w][1], redA[w][2]);
      idw_out(b, qn0, q0x, q0y, q0z, m0, m1, m2, P1, F1, out);
    }
    if (tid == 1 && v1) {
      u64 m0 = redC[0][0], m1 = redC[0][1], m2 = redC[0][2];
#pragma unroll
      for (int w = 1; w < 4; ++w) merge3(m0, m1, m2, redC[w][0], redC[w][1], redC[w][2]);
      idw_out(b, qn1, q1x, q1y, q1z, m0, m1, m2, P1, F1, out);
    }
    __syncthreads();  // protect red arrays before next iteration
  }
}

extern "C" void kernel_launch(void* const* d_in, const int* in_sizes, int n_in,
                              void* d_out, int out_size, void* d_ws, size_t ws_size,
                              hipStream_t stream) {
  const float* pos1 = (const float*)d_in[0];
  const float* pos2 = (const float*)d_in[1];
  const float* flow1 = (const float*)d_in[2];
  float* out = (float*)d_out;

  // ws layout (16B-aligned sections)
  char* ws = (char*)d_ws;
  int* counts = (int*)ws;                                   // NCT2 ints
  int* fbcnt = counts + NCT2;                               // 4 ints (zeroed with counts)
  size_t offs_off = (((size_t)NCT2 + 4) * 4 + 15) & ~(size_t)15;
  int* offs = (int*)(ws + offs_off);                        // NCT2+1 ints
  size_t part_off = (offs_off + ((size_t)NCT2 + 1) * 4 + 15) & ~(size_t)15;
  int* partials = (int*)(ws + part_off);                    // SB ints
  size_t ql_off = (part_off + (size_t)SB * 4 + 15) & ~(size_t)15;
  int* qlist = (int*)(ws + ql_off);                         // BBNN ints
  size_t fbq_off = (ql_off + (size_t)BBNN * 4 + 15) & ~(size_t)15;
  int* fbq = (int*)(ws + fbq_off);                          // BBNN ints
  size_t csr_off = (fbq_off + (size_t)BBNN * 4 + 15) & ~(size_t)15;
  float4* csr = (float4*)(ws + csr_off);                    // BBNN float4

  k_zero<<<dim3((NZ4 + 255) / 256), dim3(256), 0, stream>>>((int4*)counts);
  k_count<<<dim3(2 * BBNN / 256), dim3(256), 0, stream>>>(pos1, pos2, flow1, counts);
  k_scan1<<<dim3(SB), dim3(256), 0, stream>>>(counts, offs, partials);
  k_final<<<dim3(SB), dim3(256), 0, stream>>>(offs, partials);
  k_scat<<<dim3(2 * BBNN / 256), dim3(256), 0, stream>>>(pos1, pos2, flow1, counts,
                                                         offs, csr, qlist);
  k_query<<<dim3(BBNN * 16 / 256), dim3(256), 0, stream>>>(pos1, pos2, flow1, offs,
                                                           csr, qlist, out, fbcnt, fbq);
  k_fallback<<<dim3(128, BB), dim3(256), 0, stream>>>(pos1, pos2, flow1, fbcnt, fbq, out);
}

// Round 15
// 71.048 us; speedup vs baseline: 2.2516x; 1.0204x over previous
//
#include <hip/hip_runtime.h>
#include <math.h>

// PointWarping: B=4, C=3, N=8192 fp32. Exact 3-NN via spatial grid + IDW warp.
//
// 6 dispatches:
//  k_zero  : zero counts + scanst + fbcnt
//  k_count : bin DB points (pos1+flow1), atomic counts
//  k_scan  : single-kernel exclusive scan (decoupled lookback, wave-parallel)
//            + re-zero counts for scatter ranks
//  k_scat  : DB -> packed csr float4 (L2-resident, 512 KB)
//  k_query : 32 lanes/query, each lane owns ONE 5-cell CSR column (balanced),
//            4-wide candidate batching, 5-step butterfly merge; failed -> queue
//  k_fallback : block per 2 queued queries, 4-wide streamed brute scan
//
// Exactness: cells h=0.22 on [-3.3,3.3]^3 (clamped). Any DB point >=3 cells
// away in some axis is > 2h=0.44 away (clamped points are farther than their
// cell box), so 3rd-best d^2 <= 0.44^2*0.999 proves the top-3 exact; else
// brute-scan (also out-of-range queries). Keys are exact u64 (d2_bits<<32|idx):
// fp32-exact, (d2,idx)-lex == top_k tie-break, independent of atomic rank order.

#define BB 4
#define NN 8192
#define BBNN (BB * NN)            // 32768
#define NC 30
#define NCELLS (NC * NC * NC)     // 27000
#define NCT (BB * NCELLS)         // 108000
#define GRID_R 3.3f
#define GRID_INVH (1.0f / 0.22f)
#define D3_THR (0.44f * 0.44f * 0.999f)
#define EPB 1024
#define SB 106                    // ceil(NCT/EPB)
#define NZ4 ((NCT + 108 + 4) / 4) // counts + scanst(pad 108) + fbcnt[4]
#define ST_PART 0x40000000u
#define ST_DONE 0x80000000u
#define ST_VAL 0x3FFFFFFFu

typedef unsigned long long u64;

__device__ __forceinline__ int cell_of(float x) {
  int c = (int)floorf((x + GRID_R) * GRID_INVH);
  return min(max(c, 0), NC - 1);
}

__device__ __forceinline__ void merge3(u64& a0, u64& a1, u64& a2,
                                       u64 b0, u64 b1, u64 b2) {
  const u64 lo0 = a0 < b0 ? a0 : b0;
  const u64 hi0 = a0 < b0 ? b0 : a0;
  const u64 lo1 = a1 < b1 ? a1 : b1;
  const u64 lo2 = a2 < b2 ? a2 : b2;
  const u64 o1 = hi0 < lo1 ? hi0 : lo1;
  const u64 t = hi0 < lo1 ? lo1 : hi0;
  a0 = lo0;
  a1 = o1;
  a2 = t < lo2 ? t : lo2;
}

__device__ __forceinline__ void insert3(u64& s0, u64& s1, u64& s2, u64 key) {
  const bool c0 = key < s0;
  const bool c1 = key < s1;
  const bool c2 = key < s2;
  s2 = c1 ? s1 : (c2 ? key : s2);
  s1 = c0 ? s0 : (c1 ? key : s1);
  s0 = c0 ? key : s0;
}

__device__ __forceinline__ void wave_merge3(u64& s0, u64& s1, u64& s2) {
#pragma unroll
  for (int mask = 32; mask >= 1; mask >>= 1) {
    const u64 b0 = __shfl_xor(s0, mask, 64);
    const u64 b1 = __shfl_xor(s1, mask, 64);
    const u64 b2 = __shfl_xor(s2, mask, 64);
    merge3(s0, s1, s2, b0, b1, b2);
  }
}

__device__ __forceinline__ void cand1(const float4& a, float qx, float qy,
                                      float qz, u64& s0, u64& s1, u64& s2) {
  const float dx = a.x - qx, dy = a.y - qy, dz = a.z - qz;
  const float d2 = fmaf(dx, dx, fmaf(dy, dy, dz * dz));
  insert3(s0, s1, s2,
          ((u64)__float_as_uint(d2) << 32) | (unsigned)__float_as_uint(a.w));
}

__device__ __forceinline__ void idw_out(int b, int qn, float qx, float qy,
                                        float qz, u64 s0, u64 s1, u64 s2,
                                        const float* __restrict__ P1,
                                        const float* __restrict__ F1,
                                        float* __restrict__ out) {
  const int idxs[3] = {(int)(unsigned)s0 & (NN - 1),
                       (int)(unsigned)s1 & (NN - 1),
                       (int)(unsigned)s2 & (NN - 1)};
  float w[3], gfx[3], gfy[3], gfz[3];
  float wsumv = 0.0f;
#pragma unroll
  for (int r = 0; r < 3; ++r) {
    const int idx = idxs[r];
    const float fx = F1[idx], fy = F1[NN + idx], fz = F1[2 * NN + idx];
    const float kx = P1[idx] + fx;
    const float ky = P1[NN + idx] + fy;
    const float kz = P1[2 * NN + idx] + fz;
    const float dx = kx - qx, dy = ky - qy, dz = kz - qz;
    float d = sqrtf(dx * dx + dy * dy + dz * dz);
    d = fmaxf(d, 1e-10f);
    const float inv = 1.0f / d;
    w[r] = inv; wsumv += inv;
    gfx[r] = fx; gfy[r] = fy; gfz[r] = fz;
  }
  const float invw = 1.0f / wsumv;
  float ox = 0.0f, oy = 0.0f, oz = 0.0f;
#pragma unroll
  for (int r = 0; r < 3; ++r) {
    const float ww = w[r] * invw;
    ox = fmaf(ww, gfx[r], ox);
    oy = fmaf(ww, gfy[r], oy);
    oz = fmaf(ww, gfz[r], oz);
  }
  ox = qx - ox; oy = qy - oy; oz = qz - oz;
  ox = fminf(fmaxf(ox, -10.0f), 10.0f);
  oy = fminf(fmaxf(oy, -10.0f), 10.0f);
  oz = fminf(fmaxf(oz, -10.0f), 10.0f);
  float* o = out + (size_t)b * 3 * NN;
  o[qn] = ox;
  o[NN + qn] = oy;
  o[2 * NN + qn] = oz;
}

__global__ __launch_bounds__(256) void k_zero(int4* __restrict__ p) {
  const int i = blockIdx.x * 256 + threadIdx.x;
  if (i < NZ4) p[i] = make_int4(0, 0, 0, 0);
}

__global__ __launch_bounds__(256) void k_count(const float* __restrict__ p1,
                                               const float* __restrict__ f1,
                                               int* __restrict__ counts) {
  const int gid = blockIdx.x * 256 + threadIdx.x;  // 0..32767
  const int b = gid >> 13, n = gid & (NN - 1);
  const float* P = p1 + (size_t)b * 3 * NN;
  const float* F = f1 + (size_t)b * 3 * NN;
  const float x = P[n] + F[n];
  const float y = P[NN + n] + F[NN + n];
  const float z = P[2 * NN + n] + F[2 * NN + n];
  const int cid = (cell_of(z) * NC + cell_of(y)) * NC + cell_of(x);
  atomicAdd(&counts[b * NCELLS + cid], 1);
}

// one-kernel exclusive scan with wave-parallel decoupled lookback
__global__ __launch_bounds__(256) void k_scan(int* __restrict__ counts,
                                              int* __restrict__ offs,
                                              unsigned* __restrict__ scanst) {
  __shared__ int wsums[4];
  __shared__ int sbase;
  const int tid = threadIdx.x, lane = tid & 63, wav = tid >> 6;
  const int bid = blockIdx.x;
  const int c = bid * EPB + tid * 4;
  int4 v = make_int4(0, 0, 0, 0);
  if (c < NCT) {
    v = *reinterpret_cast<const int4*>(counts + c);
    *reinterpret_cast<int4*>(counts + c) = make_int4(0, 0, 0, 0);  // rank reset
  }
  const int sum4 = v.x + v.y + v.z + v.w;
  int incl = sum4;
  for (int off = 1; off < 64; off <<= 1) {
    const int t = __shfl_up(incl, off, 64);
    incl += (lane >= off) ? t : 0;
  }
  if (lane == 63) wsums[wav] = incl;
  __syncthreads();
  int wbase = 0;
#pragma unroll
  for (int w = 0; w < 4; ++w) wbase += (w < wav) ? wsums[w] : 0;
  const int btot = wsums[0] + wsums[1] + wsums[2] + wsums[3];

  if (wav == 0) {
    if (lane == 0) atomicExch(&scanst[bid], ST_PART | (unsigned)btot);
    int base = 0;
    int j0 = bid;
    while (j0 > 0) {
      const int j = j0 - 64 + lane;
      unsigned s;
      if (j >= 0) {
        do { s = atomicAdd(&scanst[j], 0u); } while (s == 0u);
      } else {
        s = ST_DONE;  // fake inclusive 0 below the window
      }
      const u64 dball = __ballot((s & ST_DONE) != 0);
      int val;
      if (dball) {
        const int hi = 63 - __clzll(dball);  // nearest DONE predecessor
        val = (lane >= hi) ? (int)(s & ST_VAL) : 0;
      } else {
        val = (int)(s & ST_VAL);
      }
      for (int off = 32; off >= 1; off >>= 1) val += __shfl_down(val, off, 64);
      base += __shfl(val, 0, 64);
      if (dball) break;
      j0 -= 64;
    }
    if (lane == 0) {
      atomicExch(&scanst[bid], ST_DONE | (unsigned)(base + btot));
      sbase = base;
    }
  }
  __syncthreads();
  const int excl = sbase + wbase + incl - sum4;
  if (c < NCT) {
    int4 e;
    e.x = excl;
    e.y = excl + v.x;
    e.z = e.y + v.y;
    e.w = e.z + v.z;
    *reinterpret_cast<int4*>(offs + c) = e;
  }
  if (bid == SB - 1 && tid == 0) offs[NCT] = BBNN;
}

__global__ __launch_bounds__(256) void k_scat(const float* __restrict__ p1,
                                              const float* __restrict__ f1,
                                              int* __restrict__ counts,
                                              const int* __restrict__ offs,
                                              float4* __restrict__ csr) {
  const int gid = blockIdx.x * 256 + threadIdx.x;
  const int b = gid >> 13, n = gid & (NN - 1);
  const float* P = p1 + (size_t)b * 3 * NN;
  const float* F = f1 + (size_t)b * 3 * NN;
  const float x = P[n] + F[n];
  const float y = P[NN + n] + F[NN + n];
  const float z = P[2 * NN + n] + F[2 * NN + n];
  const int cid = (cell_of(z) * NC + cell_of(y)) * NC + cell_of(x);
  const int g = b * NCELLS + cid;
  const int rank = atomicAdd(&counts[g], 1);
  csr[offs[g] + rank] = make_float4(x, y, z, __int_as_float(n));
}

// scan one contiguous CSR run with 4-wide load batching
__device__ __forceinline__ void scan_col(int st, int en,
                                         const float4* __restrict__ csr,
                                         float qx, float qy, float qz,
                                         u64& s0, u64& s1, u64& s2) {
  int j = st;
  for (; j + 4 <= en; j += 4) {
    const float4 a = csr[j];
    const float4 b = csr[j + 1];
    const float4 c = csr[j + 2];
    const float4 d = csr[j + 3];
    cand1(a, qx, qy, qz, s0, s1, s2);
    cand1(b, qx, qy, qz, s0, s1, s2);
    cand1(c, qx, qy, qz, s0, s1, s2);
    cand1(d, qx, qy, qz, s0, s1, s2);
  }
  for (; j < en; ++j) {
    const float4 a = csr[j];
    cand1(a, qx, qy, qz, s0, s1, s2);
  }
}

// 32 lanes per query; lane r (r<25) owns exactly one (dz,dy) CSR column.
__global__ __launch_bounds__(256) void k_query(const float* __restrict__ p1,
                                               const float* __restrict__ p2,
                                               const float* __restrict__ f1,
                                               const int* __restrict__ offs,
                                               const float4* __restrict__ csr,
                                               float* __restrict__ out,
                                               int* __restrict__ fbcnt,
                                               int* __restrict__ fbq) {
  const int gtid = blockIdx.x * 256 + threadIdx.x;  // 0..1048575
  const int qid = gtid >> 5;
  const int r = gtid & 31;
  const int b = qid >> 13;
  const int qn = qid & (NN - 1);
  const float* P1 = p1 + (size_t)b * 3 * NN;
  const float* P2 = p2 + (size_t)b * 3 * NN;
  const float* F1 = f1 + (size_t)b * 3 * NN;

  const float qx = P2[qn], qy = P2[NN + qn], qz = P2[2 * NN + qn];
  const bool oor = !(fabsf(qx) < GRID_R && fabsf(qy) < GRID_R && fabsf(qz) < GRID_R);

  u64 s0 = ~0ULL, s1 = ~0ULL, s2 = ~0ULL;

  if (!oor && r < 25) {
    const int qcx = cell_of(qx), qcy = cell_of(qy), qcz = cell_of(qz);
    const int gxl = max(qcx - 2, 0);
    const int span = min(qcx + 2, NC - 1) - gxl + 1;
    const int dzi = (r * 205) >> 10;  // r/5 for r<=24
    const int gz = qcz + dzi - 2;
    const int gy = qcy + (r - dzi * 5) - 2;
    if (((unsigned)gz < NC) & ((unsigned)gy < NC)) {
      const int ia = b * NCELLS + (gz * NC + gy) * NC + gxl;
      const int st = offs[ia];
      const int en = offs[ia + span];
      scan_col(st, en, csr, qx, qy, qz, s0, s1, s2);
    }
  }

  // merge the 32 partial triples of this query (5 butterfly steps)
#pragma unroll
  for (int mask = 1; mask <= 16; mask <<= 1) {
    const u64 b0 = __shfl_xor(s0, mask, 64);
    const u64 b1 = __shfl_xor(s1, mask, 64);
    const u64 b2 = __shfl_xor(s2, mask, 64);
    merge3(s0, s1, s2, b0, b1, b2);
  }

  if (r == 0) {
    const float d3 = __uint_as_float((unsigned)(s2 >> 32));
    const bool ok = !oor && (d3 <= D3_THR);  // NaN-safe: <3 cands -> fallback
    if (!ok) {
      const int slot = atomicAdd(&fbcnt[b], 1);
      fbq[b * NN + slot] = qn;
    } else {
      idw_out(b, qn, qx, qy, qz, s0, s1, s2, P1, F1, out);
    }
  }
}

// block per 2 queued queries; 256 threads stream all 8192 points, 4-wide.
__global__ __launch_bounds__(256) void k_fallback(const float* __restrict__ p1,
                                                  const float* __restrict__ p2,
                                                  const float* __restrict__ f1,
                                                  const int* __restrict__ fbcnt,
                                                  const int* __restrict__ fbq,
                                                  float* __restrict__ out) {
  __shared__ u64 redA[4][3];
  __shared__ u64 redC[4][3];
  const int b = blockIdx.y;
  const int nfb = fbcnt[b];
  const int tid = threadIdx.x, lane = tid & 63, wav = tid >> 6;
  const float* P1 = p1 + (size_t)b * 3 * NN;
  const float* P2 = p2 + (size_t)b * 3 * NN;
  const float* F1 = f1 + (size_t)b * 3 * NN;
  const int* q = fbq + b * NN;

  for (int base = blockIdx.x * 2; base < nfb; base += gridDim.x * 2) {
    const bool v1 = base + 1 < nfb;
    const int qn0 = q[base] & (NN - 1);
    const int qn1 = (v1 ? q[base + 1] : q[base]) & (NN - 1);
    const float q0x = P2[qn0], q0y = P2[NN + qn0], q0z = P2[2 * NN + qn0];
    const float q1x = P2[qn1], q1y = P2[NN + qn1], q1z = P2[2 * NN + qn1];

    u64 a0 = ~0ULL, a1 = ~0ULL, a2 = ~0ULL;
    u64 c0 = ~0ULL, c1 = ~0ULL, c2 = ~0ULL;

    for (int g0 = 0; g0 < NN; g0 += 1024) {
      const int g = g0 + tid;
      float xs[4], ys[4], zs[4];
#pragma unroll
      for (int k = 0; k < 4; ++k) {
        const int gg = g + k * 256;
        xs[k] = P1[gg] + F1[gg];
        ys[k] = P1[NN + gg] + F1[NN + gg];
        zs[k] = P1[2 * NN + gg] + F1[2 * NN + gg];
      }
#pragma unroll
      for (int k = 0; k < 4; ++k) {
        const unsigned gg = (unsigned)(g + k * 256);
        {
          const float dx = xs[k] - q0x, dy = ys[k] - q0y, dz = zs[k] - q0z;
          const float d2 = fmaf(dx, dx, fmaf(dy, dy, dz * dz));
          insert3(a0, a1, a2, ((u64)__float_as_uint(d2) << 32) | gg);
        }
        {
          const float dx = xs[k] - q1x, dy = ys[k] - q1y, dz = zs[k] - q1z;
          const float d2 = fmaf(dx, dx, fmaf(dy, dy, dz * dz));
          insert3(c0, c1, c2, ((u64)__float_as_uint(d2) << 32) | gg);
        }
      }
    }

    wave_merge3(a0, a1, a2);
    wave_merge3(c0, c1, c2);
    if (lane == 0) {
      redA[wav][0] = a0; redA[wav][1] = a1; redA[wav][2] = a2;
      redC[wav][0] = c0; redC[wav][1] = c1; redC[wav][2] = c2;
    }
    __syncthreads();
    if (tid == 0) {
      u64 m0 = redA[0][0], m1 = redA[0][1], m2 = redA[0][2];
#pragma unroll
      for (int w = 1; w < 4; ++w) merge3(m0, m1, m2, redA[w][0], redA[w][1], redA[w][2]);
      idw_out(b, qn0, q0x, q0y, q0z, m0, m1, m2, P1, F1, out);
    }
    if (tid == 1 && v1) {
      u64 m0 = redC[0][0], m1 = redC[0][1], m2 = redC[0][2];
#pragma unroll
      for (int w = 1; w < 4; ++w) merge3(m0, m1, m2, redC[w][0], redC[w][1], redC[w][2]);
      idw_out(b, qn1, q1x, q1y, q1z, m0, m1, m2, P1, F1, out);
    }
    __syncthreads();  // protect red arrays before next iteration
  }
}

extern "C" void kernel_launch(void* const* d_in, const int* in_sizes, int n_in,
                              void* d_out, int out_size, void* d_ws, size_t ws_size,
                              hipStream_t stream) {
  const float* pos1 = (const float*)d_in[0];
  const float* pos2 = (const float*)d_in[1];
  const float* flow1 = (const float*)d_in[2];
  float* out = (float*)d_out;

  // ws layout (16B-aligned sections)
  char* ws = (char*)d_ws;
  int* counts = (int*)ws;                                   // NCT ints
  unsigned* scanst = (unsigned*)(counts + NCT);             // 106 (pad 108)
  int* fbcnt = (int*)(counts + NCT + 108);                  // 4 ints
  size_t offs_off = (size_t)(NCT + 112) * 4;                // 432448, 16B-aligned
  int* offs = (int*)(ws + offs_off);                        // NCT+1 ints
  size_t fbq_off = (offs_off + ((size_t)NCT + 1) * 4 + 15) & ~(size_t)15;
  int* fbq = (int*)(ws + fbq_off);                          // BBNN ints
  size_t csr_off = (fbq_off + (size_t)BBNN * 4 + 15) & ~(size_t)15;
  float4* csr = (float4*)(ws + csr_off);                    // BBNN float4

  k_zero<<<dim3((NZ4 + 255) / 256), dim3(256), 0, stream>>>((int4*)counts);
  k_count<<<dim3(BBNN / 256), dim3(256), 0, stream>>>(pos1, flow1, counts);
  k_scan<<<dim3(SB), dim3(256), 0, stream>>>(counts, offs, scanst);
  k_scat<<<dim3(BBNN / 256), dim3(256), 0, stream>>>(pos1, flow1, counts, offs, csr);
  k_query<<<dim3(BBNN * 32 / 256), dim3(256), 0, stream>>>(pos1, pos2, flow1, offs,
                                                           csr, out, fbcnt, fbq);
  k_fallback<<<dim3(128, BB), dim3(256), 0, stream>>>(pos1, pos2, flow1, fbcnt, fbq, out);
}